// Round 3
// baseline (293.427 us; speedup 1.0000x reference)
//
#include <hip/hip_runtime.h>
#include <hip/hip_bf16.h>
#include <cstdint>
#include <cstddef>

#define DIMD 1024
#define LSEQ 4096
#define BATCH 4
#define MTOT (BATCH*LSEQ)          // 16384
#define NCHUNK 64
#define CHUNKLEN 64                // NCHUNK*CHUNKLEN == LSEQ
#define GATE_ELEMS ((size_t)MTOT*DIMD)
#define NTILE_K 16                 // 1024 / 64

typedef __bf16 bf16x8 __attribute__((ext_vector_type(8)));
typedef float f32x4 __attribute__((ext_vector_type(4)));

__device__ __forceinline__ unsigned short f2bf(float f) {
    union { float f; uint32_t u; } v; v.f = f;
    uint32_t r = v.u + 0x7fffu + ((v.u >> 16) & 1u);   // RNE
    return (unsigned short)(r >> 16);
}
__device__ __forceinline__ float bits2f(unsigned short b) {
    union { uint32_t u; float f; } v; v.u = ((uint32_t)b) << 16; return v.f;
}
__device__ __forceinline__ float gld(const float* p, size_t o) { return p[o]; }
__device__ __forceinline__ float gld(const unsigned short* p, size_t o) { return bits2f(p[o]); }
__device__ __forceinline__ void  gst(float* p, size_t o, float v) { p[o] = v; }
__device__ __forceinline__ void  gst(unsigned short* p, size_t o, float v) { p[o] = f2bf(v); }

__device__ __forceinline__ float fsig(float x) {
    return __builtin_amdgcn_rcpf(1.f + __expf(-x));
}

// ---------------- cast fp32 -> bf16 (vectorized 8/thread) ----------------
__global__ void cast_f32_to_bf16(const float* __restrict__ src,
                                 unsigned short* __restrict__ dst, int n) {
    int i = (blockIdx.x * blockDim.x + threadIdx.x) * 8;
    if (i >= n) return;
    float4 a = *(const float4*)(src + i);
    float4 b = *(const float4*)(src + i + 4);
    uint4 o;
    o.x = (uint32_t)f2bf(a.x) | ((uint32_t)f2bf(a.y) << 16);
    o.y = (uint32_t)f2bf(a.z) | ((uint32_t)f2bf(a.w) << 16);
    o.z = (uint32_t)f2bf(b.x) | ((uint32_t)f2bf(b.y) << 16);
    o.w = (uint32_t)f2bf(b.z) | ((uint32_t)f2bf(b.w) << 16);
    *(uint4*)(dst + i) = o;
}

// ---------------- 256x256-tile 8-wave deep-pipelined 4-gate GEMM ----------------
// C[m,n] = sum_k Xb[m,k]*Wcat[n,k]; tile 256x256, BK=64, 16 K-tiles.
// LDS: A 4 half-slots (2 dbuf x 2 M-half) of 16KB + B same = 128KB.
// T2 XOR swizzle: LDS linear (r, s) holds global col-group (s ^ (r&7)); reads XOR back.
// T3/T4: stage tile t+1 first, then counted vmcnt(8); never drain in main loop.
// T5: setprio(1) around each 16-MFMA quadrant.
template <typename T>
__global__ __launch_bounds__(512, 2) void gemm_gates8(
    const unsigned short* __restrict__ Xb,    // [16384][1024] bf16 bits
    const unsigned short* __restrict__ Wcat,  // [4096][1024]  bf16 bits
    const float* __restrict__ bf_, const float* __restrict__ bi_,
    const float* __restrict__ big_, const float* __restrict__ bog_,
    T* __restrict__ G)                        // [4][16384][1024]
{
    __shared__ __align__(16) char lds[131072];
    char* ldsA = lds;            // 4 x 16KB slots
    char* ldsB = lds + 65536;    // 4 x 16KB slots

    const int tid = threadIdx.x;
    const int wave = tid >> 6, lane = tid & 63;
    const int wm = wave >> 2, wn = wave & 3;       // 2 x 4 wave grid
    const int l15 = lane & 15, l4 = lane >> 4;

    // T1: bijective XCD swizzle (1024 blocks, 1024%8==0), nt-major chunks
    const int wg = blockIdx.x;
    const int swz = (wg & 7) * 128 + (wg >> 3);
    const int mt = swz & 63, nt = swz >> 6;
    const int m0 = mt * 256, n0 = nt * 256;

    // stage one operand's full K-tile (2 M-halves x 2 loads/thread = 4 gload_lds)
    auto stage = [&](const unsigned short* src, int rowbase, int k0, char* region, int buf) {
#pragma unroll
        for (int half = 0; half < 2; ++half) {
            char* slot = region + (buf * 2 + half) * 16384;
#pragma unroll
            for (int j = 0; j < 2; ++j) {
                int r = (tid >> 3) + j * 64;                 // row 0..127 within half
                int scol = (tid & 7) ^ (r & 7);              // inverse-swizzled src col-group
                const unsigned short* g = src + (size_t)(rowbase + half * 128 + r) * DIMD + k0 + scol * 8;
                __builtin_amdgcn_global_load_lds(
                    (const __attribute__((address_space(1))) uint32_t*)g,
                    (__attribute__((address_space(3))) uint32_t*)(slot + (wave << 10) + (j << 13)),
                    16, 0, 0);
            }
        }
    };

    f32x4 acc[8][4];
#pragma unroll
    for (int m = 0; m < 8; ++m)
#pragma unroll
        for (int n = 0; n < 4; ++n) acc[m][n] = (f32x4)0.f;

    // prologue: stage tile 0 into buf 0
    stage(Xb, m0, 0, ldsA, 0);
    stage(Wcat, n0, 0, ldsB, 0);

#pragma unroll 1
    for (int t = 0; t < NTILE_K; ++t) {
        const int buf = t & 1;
        if (t + 1 < NTILE_K) {
            stage(Xb, m0, (t + 1) * 64, ldsA, buf ^ 1);
            stage(Wcat, n0, (t + 1) * 64, ldsB, buf ^ 1);
            asm volatile("s_waitcnt vmcnt(8)" ::: "memory");   // tile t landed; t+1 in flight
        } else {
            asm volatile("s_waitcnt vmcnt(0)" ::: "memory");   // last tile: drain (no loss)
        }
        __builtin_amdgcn_s_barrier();

        const char* Aslot = ldsA + (buf * 2 + wm) * 16384;
        const char* Bslot = ldsB + (buf * 2 + (wn >> 1)) * 16384;

#pragma unroll
        for (int q = 0; q < 4; ++q) {
            const int mq = q >> 1, nq = q & 1;
            bf16x8 av[4][2], bv[2][2];
#pragma unroll
            for (int i = 0; i < 4; ++i)
#pragma unroll
                for (int kk = 0; kk < 2; ++kk) {
                    int r = (mq * 4 + i) * 16 + l15;
                    int s = kk * 4 + l4;
                    av[i][kk] = *(const bf16x8*)(Aslot + r * 128 + ((s ^ (r & 7)) << 4));
                }
#pragma unroll
            for (int i = 0; i < 2; ++i)
#pragma unroll
                for (int kk = 0; kk < 2; ++kk) {
                    int r = (wn & 1) * 64 + (nq * 2 + i) * 16 + l15;
                    int s = kk * 4 + l4;
                    bv[i][kk] = *(const bf16x8*)(Bslot + r * 128 + ((s ^ (r & 7)) << 4));
                }
            __builtin_amdgcn_s_barrier();
            __builtin_amdgcn_s_setprio(1);
#pragma unroll
            for (int kk = 0; kk < 2; ++kk)
#pragma unroll
                for (int i = 0; i < 4; ++i)
#pragma unroll
                    for (int i2 = 0; i2 < 2; ++i2)
                        acc[mq * 4 + i][nq * 2 + i2] = __builtin_amdgcn_mfma_f32_16x16x32_bf16(
                            av[i][kk], bv[i2][kk], acc[mq * 4 + i][nq * 2 + i2], 0, 0, 0);
            __builtin_amdgcn_s_setprio(0);
            __builtin_amdgcn_s_barrier();
        }
    }

    // epilogue: bias + activation + store (tile entirely within one gate: 256 | 1024)
    const int gate = n0 >> 10;
    const float* bias = (gate == 0) ? bf_ : (gate == 1) ? bi_ : (gate == 2) ? big_ : bog_;
    T* Gg = G + (size_t)gate * GATE_ELEMS;
    const int ebase = (n0 & 1023) + wn * 64;
    const int rowb0 = m0 + wm * 128;
#pragma unroll
    for (int nf = 0; nf < 4; ++nf) {
        int e = ebase + nf * 16 + l15;
        float bvv = bias[e];
#pragma unroll
        for (int mf = 0; mf < 8; ++mf) {
            int rowb = rowb0 + mf * 16 + l4 * 4;
#pragma unroll
            for (int r = 0; r < 4; ++r) {
                float pre = acc[mf][nf][r] + bvv;
                float v = (gate == 1) ? (2.f * fsig(2.f * pre) - 1.f) : fsig(pre);
                gst(Gg, (size_t)(rowb + r) * DIMD + e, v);
            }
        }
    }
}

// ---------------- scan phase 1: per-chunk affine aggregates ----------------
template <typename T>
__global__ void scan_phase1(const T* __restrict__ F, const T* __restrict__ TI,
                            const T* __restrict__ SG,
                            float* __restrict__ Aagg, float* __restrict__ Bagg) {
    const int d = blockIdx.x * blockDim.x + threadIdx.x;  // 0..1023
    const int c = blockIdx.y, b = blockIdx.z;
    size_t base = ((size_t)b * LSEQ + (size_t)c * CHUNKLEN) * DIMD + d;
    float A = 1.f, Bv = 0.f;
#pragma unroll 8
    for (int t = 0; t < CHUNKLEN; ++t) {
        size_t off = base + (size_t)t * DIMD;
        float f = gld(F, off);
        float i = gld(TI, off) * gld(SG, off);
        A *= f;
        Bv = __builtin_fmaf(f, Bv, i);
    }
    size_t o = ((size_t)b * NCHUNK + c) * DIMD + d;
    Aagg[o] = A;
    Bagg[o] = Bv;
}

// ---------------- scan phase 2: sequential scan over chunk aggregates ----------------
__global__ void scan_phase2(const float* __restrict__ Aagg, const float* __restrict__ Bagg,
                            const float* __restrict__ hidden,
                            float* __restrict__ Hstart, float* __restrict__ out_h) {
    int idx = blockIdx.x * blockDim.x + threadIdx.x;  // 0..4095
    int b = idx >> 10, d = idx & 1023;
    float h = hidden[b * 1024 + d];
    for (int c = 0; c < NCHUNK; ++c) {
        size_t o = ((size_t)b * NCHUNK + c) * DIMD + d;
        Hstart[o] = h;
        h = __builtin_fmaf(Aagg[o], h, Bagg[o]);
    }
    out_h[b * 1024 + d] = h;
}

// ---------------- scan phase 3: replay chunk with prefix, write y ----------------
template <typename T>
__global__ void scan_phase3(const T* __restrict__ F, const T* __restrict__ TI,
                            const T* __restrict__ SG, const T* __restrict__ OG,
                            const float* __restrict__ Hstart, float* __restrict__ y) {
    const int d = blockIdx.x * blockDim.x + threadIdx.x;
    const int c = blockIdx.y, b = blockIdx.z;
    float h = Hstart[((size_t)b * NCHUNK + c) * DIMD + d];
    size_t base = ((size_t)b * LSEQ + (size_t)c * CHUNKLEN) * DIMD + d;
#pragma unroll 4
    for (int t = 0; t < CHUNKLEN; ++t) {
        size_t off = base + (size_t)t * DIMD;
        float f = gld(F, off);
        float i = gld(TI, off) * gld(SG, off);
        h = __builtin_fmaf(f, h, i);
        y[off] = tanhf(h) * gld(OG, off);
    }
}

// ---------------- launch ----------------
extern "C" void kernel_launch(void* const* d_in, const int* in_sizes, int n_in,
                              void* d_out, int out_size, void* d_ws, size_t ws_size,
                              hipStream_t stream) {
    const float* x      = (const float*)d_in[0];
    const float* hidden = (const float*)d_in[1];
    const float* Wf  = (const float*)d_in[2];
    const float* bf_ = (const float*)d_in[3];
    const float* Wi  = (const float*)d_in[4];
    const float* bi_ = (const float*)d_in[5];
    const float* Wig = (const float*)d_in[6];
    const float* big_= (const float*)d_in[7];
    const float* Wog = (const float*)d_in[8];
    const float* bog_= (const float*)d_in[9];

    char* ws = (char*)d_ws;
    unsigned short* Xb   = (unsigned short*)(ws);            // 33,554,432 B
    unsigned short* Wcat = (unsigned short*)(ws + 33554432); //  8,388,608 B
    // gates start at 41,943,040

    float* y     = (float*)d_out;                 // [4][4096][1024]
    float* out_h = y + GATE_ELEMS;                // [4][1024]

    // casts
    cast_f32_to_bf16<<<MTOT * DIMD / 8 / 256, 256, 0, stream>>>(x, Xb, MTOT * DIMD);
    cast_f32_to_bf16<<<DIMD * DIMD / 8 / 256, 256, 0, stream>>>(Wf,  Wcat + 0 * DIMD * DIMD, DIMD * DIMD);
    cast_f32_to_bf16<<<DIMD * DIMD / 8 / 256, 256, 0, stream>>>(Wi,  Wcat + 1 * DIMD * DIMD, DIMD * DIMD);
    cast_f32_to_bf16<<<DIMD * DIMD / 8 / 256, 256, 0, stream>>>(Wig, Wcat + 2 * DIMD * DIMD, DIMD * DIMD);
    cast_f32_to_bf16<<<DIMD * DIMD / 8 / 256, 256, 0, stream>>>(Wog, Wcat + 3 * DIMD * DIMD, DIMD * DIMD);

    const size_t FP32_WS_NEED = 33554432ull + 8388608ull + GATE_ELEMS * 4 * 4 + 3ull * 1048576ull;
    if (ws_size >= FP32_WS_NEED) {
        // -------- fp32-gate path --------
        float* G      = (float*)(ws + 41943040);
        float* Aagg   = (float*)(ws + 310378496);
        float* Bagg   = (float*)(ws + 311427072);
        float* Hstart = (float*)(ws + 312475648);
        gemm_gates8<float><<<dim3(MTOT / 256 * (4096 / 256)), 512, 0, stream>>>(
            Xb, Wcat, bf_, bi_, big_, bog_, G);
        const float* Fg  = G;
        const float* TIg = G + 1 * GATE_ELEMS;
        const float* SGg = G + 2 * GATE_ELEMS;
        const float* OGg = G + 3 * GATE_ELEMS;
        scan_phase1<float><<<dim3(DIMD / 256, NCHUNK, BATCH), 256, 0, stream>>>(Fg, TIg, SGg, Aagg, Bagg);
        scan_phase2<<<BATCH * DIMD / 256, 256, 0, stream>>>(Aagg, Bagg, hidden, Hstart, out_h);
        scan_phase3<float><<<dim3(DIMD / 256, NCHUNK, BATCH), 256, 0, stream>>>(Fg, TIg, SGg, OGg, Hstart, y);
    } else {
        // -------- bf16-gate path (ws need: 179,306,496 B = 171 MiB) --------
        unsigned short* G = (unsigned short*)(ws + 41943040);
        float* Aagg   = (float*)(ws + 176160768);
        float* Bagg   = (float*)(ws + 177209344);
        float* Hstart = (float*)(ws + 178257920);
        gemm_gates8<unsigned short><<<dim3(MTOT / 256 * (4096 / 256)), 512, 0, stream>>>(
            Xb, Wcat, bf_, bi_, big_, bog_, G);
        const unsigned short* Fg  = G;
        const unsigned short* TIg = G + 1 * GATE_ELEMS;
        const unsigned short* SGg = G + 2 * GATE_ELEMS;
        const unsigned short* OGg = G + 3 * GATE_ELEMS;
        scan_phase1<unsigned short><<<dim3(DIMD / 256, NCHUNK, BATCH), 256, 0, stream>>>(Fg, TIg, SGg, Aagg, Bagg);
        scan_phase2<<<BATCH * DIMD / 256, 256, 0, stream>>>(Aagg, Bagg, hidden, Hstart, out_h);
        scan_phase3<unsigned short><<<dim3(DIMD / 256, NCHUNK, BATCH), 256, 0, stream>>>(Fg, TIg, SGg, OGg, Hstart, y);
    }
}

// Round 4
// 249.560 us; speedup vs baseline: 1.1758x; 1.1758x over previous
//
#include <hip/hip_runtime.h>
#include <hip/hip_bf16.h>
#include <cstdint>
#include <cstddef>

#define DIMD 1024
#define LSEQ 4096
#define BATCH 4
#define MTOT (BATCH*LSEQ)          // 16384
#define NCHUNK 64
#define CHUNKLEN 64                // NCHUNK*CHUNKLEN == LSEQ
#define GATE_ELEMS ((size_t)MTOT*DIMD)
#define NTILE_K 16                 // 1024 / 64

typedef __bf16 bf16x8 __attribute__((ext_vector_type(8)));
typedef float f32x4 __attribute__((ext_vector_type(4)));

__device__ __forceinline__ unsigned short f2bf(float f) {
    union { float f; uint32_t u; } v; v.f = f;
    uint32_t r = v.u + 0x7fffu + ((v.u >> 16) & 1u);   // RNE
    return (unsigned short)(r >> 16);
}
__device__ __forceinline__ float bits2f(unsigned short b) {
    union { uint32_t u; float f; } v; v.u = ((uint32_t)b) << 16; return v.f;
}
__device__ __forceinline__ float gld(const float* p, size_t o) { return p[o]; }
__device__ __forceinline__ float gld(const unsigned short* p, size_t o) { return bits2f(p[o]); }
__device__ __forceinline__ void  gst(float* p, size_t o, float v) { p[o] = v; }
__device__ __forceinline__ void  gst(unsigned short* p, size_t o, float v) { p[o] = f2bf(v); }

__device__ __forceinline__ float fsig(float x) {
    return __builtin_amdgcn_rcpf(1.f + __expf(-x));
}

// ---------------- cast fp32 -> bf16 (vectorized 8/thread) ----------------
__global__ void cast_f32_to_bf16(const float* __restrict__ src,
                                 unsigned short* __restrict__ dst, int n) {
    int i = (blockIdx.x * blockDim.x + threadIdx.x) * 8;
    if (i >= n) return;
    float4 a = *(const float4*)(src + i);
    float4 b = *(const float4*)(src + i + 4);
    uint4 o;
    o.x = (uint32_t)f2bf(a.x) | ((uint32_t)f2bf(a.y) << 16);
    o.y = (uint32_t)f2bf(a.z) | ((uint32_t)f2bf(a.w) << 16);
    o.z = (uint32_t)f2bf(b.x) | ((uint32_t)f2bf(b.y) << 16);
    o.w = (uint32_t)f2bf(b.z) | ((uint32_t)f2bf(b.w) << 16);
    *(uint4*)(dst + i) = o;
}

// ---------------- 256x256-tile 8-wave pipelined 4-gate GEMM ----------------
// Depth-2 prefetch with 2 LDS buffers: stage(t+2) issued at END of iter t,
// so tile data lands ~2 iters (~1200 cyc) before its vmcnt. 2 barriers/iter.
// Compute region: register-pipelined ds_reads, no inner barriers, setprio
// around MFMA clusters. T2 XOR swizzle on LDS (linear dest + pre-swizzled
// global src + swizzled read).
template <typename T>
__global__ __launch_bounds__(512, 1) void gemm_gates8(
    const unsigned short* __restrict__ Xb,    // [16384][1024] bf16 bits
    const unsigned short* __restrict__ Wcat,  // [4096][1024]  bf16 bits
    const float* __restrict__ bf_, const float* __restrict__ bi_,
    const float* __restrict__ big_, const float* __restrict__ bog_,
    T* __restrict__ G)                        // [4][16384][1024]
{
    __shared__ __align__(16) char lds[131072];
    char* ldsA = lds;            // 2 bufs x 32KB (2 M-halves x 16KB)
    char* ldsB = lds + 65536;

    const int tid = threadIdx.x;
    const int wave = tid >> 6, lane = tid & 63;
    const int wm = wave >> 2, wn = wave & 3;       // 2 x 4 wave grid
    const int l15 = lane & 15, l4 = lane >> 4;

    // T1: bijective XCD swizzle (1024 blocks), nt-slab per XCD
    const int wg = blockIdx.x;
    const int swz = (wg & 7) * 128 + (wg >> 3);
    const int mt = swz & 63, nt = swz >> 6;
    const int m0 = mt * 256, n0 = nt * 256;

    auto stage = [&](const unsigned short* src, int rowbase, int k0, char* region, int buf) {
#pragma unroll
        for (int half = 0; half < 2; ++half) {
            char* slot = region + (buf * 2 + half) * 16384;
#pragma unroll
            for (int j = 0; j < 2; ++j) {
                int r = (tid >> 3) + j * 64;                 // row 0..127 within half
                int scol = (tid & 7) ^ (r & 7);              // inverse-swizzled src col-group
                const unsigned short* g = src + (size_t)(rowbase + half * 128 + r) * DIMD + k0 + scol * 8;
                __builtin_amdgcn_global_load_lds(
                    (const __attribute__((address_space(1))) uint32_t*)g,
                    (__attribute__((address_space(3))) uint32_t*)(slot + (wave << 10) + (j << 13)),
                    16, 0, 0);
            }
        }
    };

    f32x4 acc[8][4];
#pragma unroll
    for (int m = 0; m < 8; ++m)
#pragma unroll
        for (int n = 0; n < 4; ++n) acc[m][n] = (f32x4)0.f;

    // prologue: stage tiles 0 and 1
    stage(Xb, m0, 0, ldsA, 0);   stage(Wcat, n0, 0, ldsB, 0);
    stage(Xb, m0, 64, ldsA, 1);  stage(Wcat, n0, 64, ldsB, 1);

#pragma unroll 1
    for (int t = 0; t < NTILE_K; ++t) {
        const int buf = t & 1;
        if (t == NTILE_K - 1) asm volatile("s_waitcnt vmcnt(0)" ::: "memory");
        else                  asm volatile("s_waitcnt vmcnt(8)" ::: "memory");
        __builtin_amdgcn_s_barrier();

        const char* Aslot = ldsA + (buf * 2 + wm) * 16384;
        const char* Bslot = ldsB + (buf * 2 + (wn >> 1)) * 16384;
        const int rbB = (wn & 1) * 64;

        // swizzled LDS read helpers
        auto rdA = [&](int mq, int i, int kk) -> bf16x8 {
            int r = (mq * 4 + i) * 16 + l15;
            int s = kk * 4 + l4;
            return *(const bf16x8*)(Aslot + r * 128 + ((s ^ (r & 7)) << 4));
        };
        auto rdB = [&](int nq, int i2, int kk) -> bf16x8 {
            int r = rbB + (nq * 2 + i2) * 16 + l15;
            int s = kk * 4 + l4;
            return *(const bf16x8*)(Bslot + r * 128 + ((s ^ (r & 7)) << 4));
        };

        bf16x8 av0[4][2], av1[4][2], bv0[2][2], bv1[2][2];
#pragma unroll
        for (int i = 0; i < 4; ++i)
#pragma unroll
            for (int kk = 0; kk < 2; ++kk) av0[i][kk] = rdA(0, i, kk);
#pragma unroll
        for (int i2 = 0; i2 < 2; ++i2)
#pragma unroll
            for (int kk = 0; kk < 2; ++kk) { bv0[i2][kk] = rdB(0, i2, kk); bv1[i2][kk] = rdB(1, i2, kk); }

        // MFMA (mq=0, nq=0)
        __builtin_amdgcn_s_setprio(1);
#pragma unroll
        for (int kk = 0; kk < 2; ++kk)
#pragma unroll
            for (int i = 0; i < 4; ++i)
#pragma unroll
                for (int i2 = 0; i2 < 2; ++i2)
                    acc[i][i2] = __builtin_amdgcn_mfma_f32_16x16x32_bf16(av0[i][kk], bv0[i2][kk], acc[i][i2], 0, 0, 0);
        __builtin_amdgcn_s_setprio(0);

        // prefetch av1 (hidden under next MFMA cluster)
#pragma unroll
        for (int i = 0; i < 4; ++i)
#pragma unroll
            for (int kk = 0; kk < 2; ++kk) av1[i][kk] = rdA(1, i, kk);

        // MFMA (mq=0, nq=1)
        __builtin_amdgcn_s_setprio(1);
#pragma unroll
        for (int kk = 0; kk < 2; ++kk)
#pragma unroll
            for (int i = 0; i < 4; ++i)
#pragma unroll
                for (int i2 = 0; i2 < 2; ++i2)
                    acc[i][2 + i2] = __builtin_amdgcn_mfma_f32_16x16x32_bf16(av0[i][kk], bv1[i2][kk], acc[i][2 + i2], 0, 0, 0);
        __builtin_amdgcn_s_setprio(0);

        // MFMA (mq=1, nq=0)
        __builtin_amdgcn_s_setprio(1);
#pragma unroll
        for (int kk = 0; kk < 2; ++kk)
#pragma unroll
            for (int i = 0; i < 4; ++i)
#pragma unroll
                for (int i2 = 0; i2 < 2; ++i2)
                    acc[4 + i][i2] = __builtin_amdgcn_mfma_f32_16x16x32_bf16(av1[i][kk], bv0[i2][kk], acc[4 + i][i2], 0, 0, 0);
        __builtin_amdgcn_s_setprio(0);

        // MFMA (mq=1, nq=1)
        __builtin_amdgcn_s_setprio(1);
#pragma unroll
        for (int kk = 0; kk < 2; ++kk)
#pragma unroll
            for (int i = 0; i < 4; ++i)
#pragma unroll
                for (int i2 = 0; i2 < 2; ++i2)
                    acc[4 + i][2 + i2] = __builtin_amdgcn_mfma_f32_16x16x32_bf16(av1[i][kk], bv1[i2][kk], acc[4 + i][2 + i2], 0, 0, 0);
        __builtin_amdgcn_s_setprio(0);

        __builtin_amdgcn_s_barrier();
        if (t + 2 < NTILE_K) {   // stage tile t+2 into the buffer just freed
            stage(Xb, m0, (t + 2) * 64, ldsA, buf);
            stage(Wcat, n0, (t + 2) * 64, ldsB, buf);
        }
    }

    // epilogue: bias + activation + store; row-major order so 64B lines complete quickly
    const int gate = n0 >> 10;
    const float* bias = (gate == 0) ? bf_ : (gate == 1) ? bi_ : (gate == 2) ? big_ : bog_;
    T* Gg = G + (size_t)gate * GATE_ELEMS;
    const int ebase = (n0 & 1023) + wn * 64;
    const int rowb0 = m0 + wm * 128;
    float bvv[4];
#pragma unroll
    for (int nf = 0; nf < 4; ++nf) bvv[nf] = bias[ebase + nf * 16 + l15];
#pragma unroll
    for (int mf = 0; mf < 8; ++mf) {
        int rowb = rowb0 + mf * 16 + l4 * 4;
#pragma unroll
        for (int r = 0; r < 4; ++r) {
            size_t rowoff = (size_t)(rowb + r) * DIMD;
#pragma unroll
            for (int nf = 0; nf < 4; ++nf) {
                float pre = acc[mf][nf][r] + bvv[nf];
                float v = (gate == 1) ? (2.f * fsig(2.f * pre) - 1.f) : fsig(pre);
                gst(Gg, rowoff + ebase + nf * 16 + l15, v);
            }
        }
    }
}

// ---------------- scan phase 1: per-chunk affine aggregates ----------------
template <typename T>
__global__ void scan_phase1(const T* __restrict__ F, const T* __restrict__ TI,
                            const T* __restrict__ SG,
                            float* __restrict__ Aagg, float* __restrict__ Bagg) {
    const int d = blockIdx.x * blockDim.x + threadIdx.x;  // 0..1023
    const int c = blockIdx.y, b = blockIdx.z;
    size_t base = ((size_t)b * LSEQ + (size_t)c * CHUNKLEN) * DIMD + d;
    float A = 1.f, Bv = 0.f;
#pragma unroll 8
    for (int t = 0; t < CHUNKLEN; ++t) {
        size_t off = base + (size_t)t * DIMD;
        float f = gld(F, off);
        float i = gld(TI, off) * gld(SG, off);
        A *= f;
        Bv = __builtin_fmaf(f, Bv, i);
    }
    size_t o = ((size_t)b * NCHUNK + c) * DIMD + d;
    Aagg[o] = A;
    Bagg[o] = Bv;
}

// ---------------- scan phase 2: sequential scan over chunk aggregates ----------------
__global__ void scan_phase2(const float* __restrict__ Aagg, const float* __restrict__ Bagg,
                            const float* __restrict__ hidden,
                            float* __restrict__ Hstart, float* __restrict__ out_h) {
    int idx = blockIdx.x * blockDim.x + threadIdx.x;  // 0..4095
    int b = idx >> 10, d = idx & 1023;
    float h = hidden[b * 1024 + d];
    for (int c = 0; c < NCHUNK; ++c) {
        size_t o = ((size_t)b * NCHUNK + c) * DIMD + d;
        Hstart[o] = h;
        h = __builtin_fmaf(Aagg[o], h, Bagg[o]);
    }
    out_h[b * 1024 + d] = h;
}

// ---------------- scan phase 3: replay chunk with prefix, write y ----------------
template <typename T>
__global__ void scan_phase3(const T* __restrict__ F, const T* __restrict__ TI,
                            const T* __restrict__ SG, const T* __restrict__ OG,
                            const float* __restrict__ Hstart, float* __restrict__ y) {
    const int d = blockIdx.x * blockDim.x + threadIdx.x;
    const int c = blockIdx.y, b = blockIdx.z;
    float h = Hstart[((size_t)b * NCHUNK + c) * DIMD + d];
    size_t base = ((size_t)b * LSEQ + (size_t)c * CHUNKLEN) * DIMD + d;
#pragma unroll 4
    for (int t = 0; t < CHUNKLEN; ++t) {
        size_t off = base + (size_t)t * DIMD;
        float f = gld(F, off);
        float i = gld(TI, off) * gld(SG, off);
        h = __builtin_fmaf(f, h, i);
        y[off] = tanhf(h) * gld(OG, off);
    }
}

// ---------------- launch ----------------
extern "C" void kernel_launch(void* const* d_in, const int* in_sizes, int n_in,
                              void* d_out, int out_size, void* d_ws, size_t ws_size,
                              hipStream_t stream) {
    const float* x      = (const float*)d_in[0];
    const float* hidden = (const float*)d_in[1];
    const float* Wf  = (const float*)d_in[2];
    const float* bf_ = (const float*)d_in[3];
    const float* Wi  = (const float*)d_in[4];
    const float* bi_ = (const float*)d_in[5];
    const float* Wig = (const float*)d_in[6];
    const float* big_= (const float*)d_in[7];
    const float* Wog = (const float*)d_in[8];
    const float* bog_= (const float*)d_in[9];

    char* ws = (char*)d_ws;
    unsigned short* Xb   = (unsigned short*)(ws);            // 33,554,432 B
    unsigned short* Wcat = (unsigned short*)(ws + 33554432); //  8,388,608 B
    // gates start at 41,943,040

    float* y     = (float*)d_out;                 // [4][4096][1024]
    float* out_h = y + GATE_ELEMS;                // [4][1024]

    // casts
    cast_f32_to_bf16<<<MTOT * DIMD / 8 / 256, 256, 0, stream>>>(x, Xb, MTOT * DIMD);
    cast_f32_to_bf16<<<DIMD * DIMD / 8 / 256, 256, 0, stream>>>(Wf,  Wcat + 0 * DIMD * DIMD, DIMD * DIMD);
    cast_f32_to_bf16<<<DIMD * DIMD / 8 / 256, 256, 0, stream>>>(Wi,  Wcat + 1 * DIMD * DIMD, DIMD * DIMD);
    cast_f32_to_bf16<<<DIMD * DIMD / 8 / 256, 256, 0, stream>>>(Wig, Wcat + 2 * DIMD * DIMD, DIMD * DIMD);
    cast_f32_to_bf16<<<DIMD * DIMD / 8 / 256, 256, 0, stream>>>(Wog, Wcat + 3 * DIMD * DIMD, DIMD * DIMD);

    const size_t FP32_WS_NEED = 33554432ull + 8388608ull + GATE_ELEMS * 4 * 4 + 3ull * 1048576ull;
    if (ws_size >= FP32_WS_NEED) {
        // -------- fp32-gate path --------
        float* G      = (float*)(ws + 41943040);
        float* Aagg   = (float*)(ws + 310378496);
        float* Bagg   = (float*)(ws + 311427072);
        float* Hstart = (float*)(ws + 312475648);
        gemm_gates8<float><<<dim3(MTOT / 256 * (4096 / 256)), 512, 0, stream>>>(
            Xb, Wcat, bf_, bi_, big_, bog_, G);
        const float* Fg  = G;
        const float* TIg = G + 1 * GATE_ELEMS;
        const float* SGg = G + 2 * GATE_ELEMS;
        const float* OGg = G + 3 * GATE_ELEMS;
        scan_phase1<float><<<dim3(DIMD / 256, NCHUNK, BATCH), 256, 0, stream>>>(Fg, TIg, SGg, Aagg, Bagg);
        scan_phase2<<<BATCH * DIMD / 256, 256, 0, stream>>>(Aagg, Bagg, hidden, Hstart, out_h);
        scan_phase3<float><<<dim3(DIMD / 256, NCHUNK, BATCH), 256, 0, stream>>>(Fg, TIg, SGg, OGg, Hstart, y);
    } else {
        // -------- bf16-gate path (ws need: 179,306,496 B = 171 MiB) --------
        unsigned short* G = (unsigned short*)(ws + 41943040);
        float* Aagg   = (float*)(ws + 176160768);
        float* Bagg   = (float*)(ws + 177209344);
        float* Hstart = (float*)(ws + 178257920);
        gemm_gates8<unsigned short><<<dim3(MTOT / 256 * (4096 / 256)), 512, 0, stream>>>(
            Xb, Wcat, bf_, bi_, big_, bog_, G);
        const unsigned short* Fg  = G;
        const unsigned short* TIg = G + 1 * GATE_ELEMS;
        const unsigned short* SGg = G + 2 * GATE_ELEMS;
        const unsigned short* OGg = G + 3 * GATE_ELEMS;
        scan_phase1<unsigned short><<<dim3(DIMD / 256, NCHUNK, BATCH), 256, 0, stream>>>(Fg, TIg, SGg, Aagg, Bagg);
        scan_phase2<<<BATCH * DIMD / 256, 256, 0, stream>>>(Aagg, Bagg, hidden, Hstart, out_h);
        scan_phase3<unsigned short><<<dim3(DIMD / 256, NCHUNK, BATCH), 256, 0, stream>>>(Fg, TIg, SGg, OGg, Hstart, y);
    }
}